// Round 6
// baseline (7477.173 us; speedup 1.0000x reference)
//
#include <hip/hip_runtime.h>
#include <stdint.h>

typedef short bf16x8 __attribute__((ext_vector_type(8)));
typedef float f32x4 __attribute__((ext_vector_type(4)));
typedef unsigned short u16;

__device__ __forceinline__ float b2f(u16 u) {
  return __uint_as_float(((unsigned)u) << 16);
}
__device__ __forceinline__ u16 f2b(float f) {
  unsigned u = __float_as_uint(f);
  return (u16)((u + 0x7fffu + ((u >> 16) & 1u)) >> 16);  // RNE
}

#define NEGINF (-1.0e30f)

// ---------------------------------------------------------------- dtype sniff
// Per-input dtype detection. fp32 signatures in the raw u16 stream:
//  (a) low mantissa halves look uniform -> many "bf16 exponents" >= 0xC0
//  (b) clean values (e.g. gamma=ones) -> even-index u16 == 0x0000
// bf16 N(0,1)/ones data shows neither. flags[i]=1 -> fp32.
__global__ void sniff5(const u16* x, const u16* wq, const u16* wo,
                       const u16* qg, const u16* kg, int* flags) {
  const u16* p;
  int S;
  switch (blockIdx.x) {
    case 0: p = x;  S = 2048; break;
    case 1: p = wq; S = 2048; break;
    case 2: p = wo; S = 2048; break;
    case 3: p = qg; S = 128;  break;
    default: p = kg; S = 128; break;
  }
  __shared__ int cbig, czero;
  if (threadIdx.x == 0) { cbig = 0; czero = 0; }
  __syncthreads();
  int cb = 0, cz = 0;
  for (int i = threadIdx.x; i < S; i += 256) {
    const u16 u = p[i];
    if (((u >> 7) & 0xFF) >= 0xC0) ++cb;
    if (!(i & 1) && u == 0) ++cz;
  }
  atomicAdd(&cbig, cb);
  atomicAdd(&czero, cz);
  __syncthreads();
  if (threadIdx.x == 0)
    flags[blockIdx.x] = (cbig > S / 32 || czero > 3 * S / 8) ? 1 : 0;
}

// ---------------------------------------------------------------- convert
__global__ __launch_bounds__(256) void conv_in(const void* __restrict__ src,
                                               u16* __restrict__ dst,
                                               const int* __restrict__ flags,
                                               int fidx, int n) {
  const int fp32 = flags[fidx];
  int i = blockIdx.x * 256 + threadIdx.x;
  const int stride = gridDim.x * 256;
  if (fp32) {
    const float* s = (const float*)src;
    for (; i < n; i += stride) dst[i] = f2b(s[i]);
  } else {
    const u16* s = (const u16*)src;
    for (; i < n; i += stride) dst[i] = s[i];
  }
}

// ---------------------------------------------------------------- transpose_in
// dst[c][r] = bf16(src[off + r*ss + c]); dual-dtype. 64x64 tiles.
__global__ __launch_bounds__(256) void transpose_in(
    const void* __restrict__ src, u16* __restrict__ dst,
    const int* __restrict__ flags, int fidx, int ss, int ds, long long off) {
  __shared__ u16 tile[64][65];
  const int fp32 = flags[fidx];
  const int rb = blockIdx.y * 64, cb = blockIdx.x * 64;
  const int cl = threadIdx.x & 63, r0 = threadIdx.x >> 6;
  if (fp32) {
    const float* s = (const float*)src + off;
#pragma unroll
    for (int i = 0; i < 16; ++i) {
      int r = r0 + i * 4;
      tile[r][cl] = f2b(s[(long long)(rb + r) * ss + cb + cl]);
    }
  } else {
    const u16* s = (const u16*)src + off;
#pragma unroll
    for (int i = 0; i < 16; ++i) {
      int r = r0 + i * 4;
      tile[r][cl] = s[(long long)(rb + r) * ss + cb + cl];
    }
  }
  __syncthreads();
#pragma unroll
  for (int i = 0; i < 16; ++i) {
    int r2 = r0 + i * 4;
    dst[(long long)(cb + r2) * ds + rb + cl] = tile[cl][r2];
  }
}

// ---------------------------------------------------------------- transpose
__global__ __launch_bounds__(256) void transpose_bf16(
    const u16* __restrict__ src, u16* __restrict__ dst, int ss, int ds,
    long long sz, long long dz) {
  __shared__ u16 tile[64][65];
  const u16* s = src + (long long)blockIdx.z * sz;
  u16* d = dst + (long long)blockIdx.z * dz;
  const int rb = blockIdx.y * 64, cb = blockIdx.x * 64;
  const int cl = threadIdx.x & 63, r0 = threadIdx.x >> 6;
#pragma unroll
  for (int i = 0; i < 16; ++i) {
    int r = r0 + i * 4;
    tile[r][cl] = s[(long long)(rb + r) * ss + cb + cl];
  }
  __syncthreads();
#pragma unroll
  for (int i = 0; i < 16; ++i) {
    int r2 = r0 + i * 4;
    d[(long long)(cb + r2) * ds + rb + cl] = tile[cl][r2];
  }
}

// ---------------------------------------------------------------- GEMM (bf16 out)
// C(MxN, stride ldc) = A(MxK) * Bt(NxK)^T, fp32 accum. 128x128 tile, BK=32.
__global__ __launch_bounds__(256) void gemm_bt(
    const u16* __restrict__ A, const u16* __restrict__ Bt, u16* __restrict__ C,
    int M, int N, int K, int ldc) {
  __shared__ __align__(16) u16 As[128 * 32];
  __shared__ __align__(16) u16 Bs[128 * 32];
  const int tid = threadIdx.x;
  const int w = tid >> 6, l = tid & 63;
  const int lane15 = l & 15, quad = l >> 4;
  const int m0 = blockIdx.y * 128, n0 = blockIdx.x * 128;
  const int wm = (w >> 1) * 64, wn = (w & 1) * 64;
  const int srow = w * 32 + (l >> 2);
  const int skoff = (l & 3) * 8;
  const u16* gA = A + (size_t)(m0 + srow) * K + skoff;
  const u16* gB = Bt + (size_t)(n0 + srow) * K + skoff;
  u16* lA = &As[w * 1024 + l * 8];
  u16* lB = &Bs[w * 1024 + l * 8];
  f32x4 acc[4][4] = {};
  const int nK = K >> 5;
  for (int kb = 0; kb < nK; ++kb) {
    bf16x8 a0 = *(const bf16x8*)gA;
    bf16x8 a1 = *(const bf16x8*)(gA + (size_t)16 * K);
    bf16x8 b0 = *(const bf16x8*)gB;
    bf16x8 b1 = *(const bf16x8*)(gB + (size_t)16 * K);
    __syncthreads();
    *(bf16x8*)lA = a0;
    *(bf16x8*)(lA + 16 * 32) = a1;
    *(bf16x8*)lB = b0;
    *(bf16x8*)(lB + 16 * 32) = b1;
    __syncthreads();
    bf16x8 af[4], bfr[4];
#pragma unroll
    for (int mi = 0; mi < 4; ++mi)
      af[mi] = *(const bf16x8*)&As[(wm + mi * 16 + lane15) * 32 + quad * 8];
#pragma unroll
    for (int ni = 0; ni < 4; ++ni)
      bfr[ni] = *(const bf16x8*)&Bs[(wn + ni * 16 + lane15) * 32 + quad * 8];
#pragma unroll
    for (int mi = 0; mi < 4; ++mi)
#pragma unroll
      for (int ni = 0; ni < 4; ++ni)
        acc[mi][ni] = __builtin_amdgcn_mfma_f32_16x16x32_bf16(
            af[mi], bfr[ni], acc[mi][ni], 0, 0, 0);
    gA += 32;
    gB += 32;
  }
#pragma unroll
  for (int mi = 0; mi < 4; ++mi)
#pragma unroll
    for (int ni = 0; ni < 4; ++ni)
#pragma unroll
      for (int r = 0; r < 4; ++r)
        C[(size_t)(m0 + wm + mi * 16 + quad * 4 + r) * ldc +
          (n0 + wn + ni * 16 + lane15)] = f2b(acc[mi][ni][r]);
}

// ---------------------------------------------------------------- GEMM (fp32 out)
// identical, but writes float C — d_out is the reference's fp32 dtype.
__global__ __launch_bounds__(256) void gemm_bt_f32(
    const u16* __restrict__ A, const u16* __restrict__ Bt,
    float* __restrict__ C, int M, int N, int K, int ldc) {
  __shared__ __align__(16) u16 As[128 * 32];
  __shared__ __align__(16) u16 Bs[128 * 32];
  const int tid = threadIdx.x;
  const int w = tid >> 6, l = tid & 63;
  const int lane15 = l & 15, quad = l >> 4;
  const int m0 = blockIdx.y * 128, n0 = blockIdx.x * 128;
  const int wm = (w >> 1) * 64, wn = (w & 1) * 64;
  const int srow = w * 32 + (l >> 2);
  const int skoff = (l & 3) * 8;
  const u16* gA = A + (size_t)(m0 + srow) * K + skoff;
  const u16* gB = Bt + (size_t)(n0 + srow) * K + skoff;
  u16* lA = &As[w * 1024 + l * 8];
  u16* lB = &Bs[w * 1024 + l * 8];
  f32x4 acc[4][4] = {};
  const int nK = K >> 5;
  for (int kb = 0; kb < nK; ++kb) {
    bf16x8 a0 = *(const bf16x8*)gA;
    bf16x8 a1 = *(const bf16x8*)(gA + (size_t)16 * K);
    bf16x8 b0 = *(const bf16x8*)gB;
    bf16x8 b1 = *(const bf16x8*)(gB + (size_t)16 * K);
    __syncthreads();
    *(bf16x8*)lA = a0;
    *(bf16x8*)(lA + 16 * 32) = a1;
    *(bf16x8*)lB = b0;
    *(bf16x8*)(lB + 16 * 32) = b1;
    __syncthreads();
    bf16x8 af[4], bfr[4];
#pragma unroll
    for (int mi = 0; mi < 4; ++mi)
      af[mi] = *(const bf16x8*)&As[(wm + mi * 16 + lane15) * 32 + quad * 8];
#pragma unroll
    for (int ni = 0; ni < 4; ++ni)
      bfr[ni] = *(const bf16x8*)&Bs[(wn + ni * 16 + lane15) * 32 + quad * 8];
#pragma unroll
    for (int mi = 0; mi < 4; ++mi)
#pragma unroll
      for (int ni = 0; ni < 4; ++ni)
        acc[mi][ni] = __builtin_amdgcn_mfma_f32_16x16x32_bf16(
            af[mi], bfr[ni], acc[mi][ni], 0, 0, 0);
    gA += 32;
    gB += 32;
  }
#pragma unroll
  for (int mi = 0; mi < 4; ++mi)
#pragma unroll
    for (int ni = 0; ni < 4; ++ni)
#pragma unroll
      for (int r = 0; r < 4; ++r)
        C[(size_t)(m0 + wm + mi * 16 + quad * 4 + r) * ldc +
          (n0 + wn + ni * 16 + lane15)] = acc[mi][ni][r];
}

// ---------------------------------------------------------------- RMSNorm+RoPE
__global__ __launch_bounds__(256) void rms_rope(
    const u16* __restrict__ in, const u16* __restrict__ gamma,
    u16* __restrict__ outr) {
  const int wid = blockIdx.x * 4 + (threadIdx.x >> 6);
  const int l = threadIdx.x & 63;
  const int n = wid >> 4;
  const int h = wid & 15;
  const u16* base = in + (size_t)n * 2048 + h * 128;
  float a = b2f(base[l]), b = b2f(base[l + 64]);
  float ssum = a * a + b * b;
#pragma unroll
  for (int m = 1; m < 64; m <<= 1) ssum += __shfl_xor(ssum, m);
  const float r = rsqrtf(ssum * (1.0f / 128.0f) + 1e-6f);
  a *= r * b2f(gamma[l]);
  b *= r * b2f(gamma[l + 64]);
  const float inv = __expf(-(float)l * 0.14391156831212787f);  // 10000^(-l/64)
  float s, c;
  sincosf((float)n * inv, &s, &c);
  const size_t o = ((size_t)h * 4096 + n) * 128 + l;
  outr[o] = f2b(a * c - b * s);
  outr[o + 64] = f2b(b * c + a * s);
}

// ---------------------------------------------------------------- row softmax
__global__ __launch_bounds__(256) void row_softmax(u16* __restrict__ S, int q0) {
  const int row = blockIdx.x * 4 + (threadIdx.x >> 6);
  const int l = threadIdx.x & 63;
  const int q_abs = q0 + row;
  u16* p = S + (size_t)row * 4096;
  const float sc = 0.08838834764831845f;  // 1/sqrt(128)
  float x[64];
  float mx = NEGINF;
#pragma unroll
  for (int i = 0; i < 64; ++i) {
    const int c = i * 64 + l;
    const float v = (c <= q_abs) ? b2f(p[c]) * sc : NEGINF;
    x[i] = v;
    mx = fmaxf(mx, v);
  }
#pragma unroll
  for (int m = 1; m < 64; m <<= 1) mx = fmaxf(mx, __shfl_xor(mx, m));
  float s = 0.f;
#pragma unroll
  for (int i = 0; i < 64; ++i) {
    const int c = i * 64 + l;
    const float e = (c <= q_abs) ? __expf(x[i] - mx) : 0.f;
    x[i] = e;
    s += e;
  }
#pragma unroll
  for (int m = 1; m < 64; m <<= 1) s += __shfl_xor(s, m);
  const float is = 1.0f / s;
#pragma unroll
  for (int i = 0; i < 64; ++i) p[i * 64 + l] = f2b(x[i] * is);
}

// ---------------------------------------------------------------- launch
// ws layout identical to r4/r5 (peak 58.8 MB). d_out is fp32 (33.5 MB);
// its first 16.7 MB doubles as bf16 scratch (v_buf then q_r) before the
// final fp32 GEMM overwrites all of it.
extern "C" void kernel_launch(void* const* d_in, const int* in_sizes, int n_in,
                              void* d_out, int out_size, void* d_ws,
                              size_t ws_size, hipStream_t stream) {
  (void)out_size; (void)ws_size;
  // identify inputs by element count (robust to ordering)
  int ix = 0, iwq = 1, iwo = 2, ig1 = 3, ig2 = 4;
  {
    int g1 = -1, g2 = -1, xx = -1, wqq = -1, woo = -1;
    for (int i = 0; i < n_in; ++i) {
      const int s = in_sizes[i];
      if (s == 8388608) xx = i;
      else if (s == 12582912) wqq = i;
      else if (s == 4194304) woo = i;
      else if (s == 128) { if (g1 < 0) g1 = i; else g2 = i; }
    }
    if (xx >= 0 && wqq >= 0 && woo >= 0 && g1 >= 0 && g2 >= 0) {
      ix = xx; iwq = wqq; iwo = woo; ig1 = g1; ig2 = g2;
    }
  }
  const void* x = d_in[ix];
  const void* wq = d_in[iwq];
  const void* wo = d_in[iwo];
  const void* qg = d_in[ig1];
  const void* kg = d_in[ig2];
  float* out = (float*)d_out;  // fp32 output, per reference dtype
  char* ws = (char*)d_ws;
  u16* xb = (u16*)(ws);
  u16* q_buf = (u16*)(ws + 16777216LL);
  u16* k_buf = (u16*)(ws + 33554432LL);
  u16* wT8 = (u16*)(ws + 50331648LL);  // also the 8.4MB S scratch
  int* flags = (int*)(ws + 58720256LL);
  u16* gq_b = (u16*)(ws + 58720512LL);
  u16* gk_b = (u16*)(ws + 58721024LL);
  u16* v_t = (u16*)(ws);                // over dead xb
  u16* k_r = (u16*)(ws + 16777216LL);   // over dead q_buf
  u16* attn = (u16*)(ws + 33554432LL);  // over dead k_buf
  u16* S = wT8;                         // (1024,4096) bf16 = 8.4MB
  u16* v_buf = (u16*)d_out;             // bf16 scratch in d_out[0:16.7MB)
  u16* q_r = (u16*)d_out;               // same region, sequentially reused

  const dim3 tg(32, 32, 1), gg(16, 32);
  sniff5<<<5, 256, 0, stream>>>((const u16*)x, (const u16*)wq, (const u16*)wo,
                                (const u16*)qg, (const u16*)kg, flags);
  conv_in<<<8192, 256, 0, stream>>>(x, xb, flags, 0, 4096 * 2048);
  conv_in<<<1, 256, 0, stream>>>(qg, gq_b, flags, 3, 128);
  conv_in<<<1, 256, 0, stream>>>(kg, gk_b, flags, 4, 128);
  // q/k/v projections through one transposed-weight slot
  transpose_in<<<tg, 256, 0, stream>>>(wq, wT8, flags, 1, 6144, 2048, 0LL);
  gemm_bt<<<gg, 256, 0, stream>>>(xb, wT8, q_buf, 4096, 2048, 2048, 2048);
  transpose_in<<<tg, 256, 0, stream>>>(wq, wT8, flags, 1, 6144, 2048, 2048LL);
  gemm_bt<<<gg, 256, 0, stream>>>(xb, wT8, k_buf, 4096, 2048, 2048, 2048);
  transpose_in<<<tg, 256, 0, stream>>>(wq, wT8, flags, 1, 6144, 2048, 4096LL);
  gemm_bt<<<gg, 256, 0, stream>>>(xb, wT8, v_buf, 4096, 2048, 2048, 2048);
  // v -> v_t (h, d, n)  (xb dead)
  transpose_bf16<<<dim3(2, 64, 16), 256, 0, stream>>>(v_buf, v_t, 2048, 4096,
                                                      128LL, 524288LL);
  // rmsnorm + rope + repack to (h,n,d)
  rms_rope<<<dim3(16384), 256, 0, stream>>>(q_buf, gq_b, q_r);
  rms_rope<<<dim3(16384), 256, 0, stream>>>(k_buf, gk_b, k_r);

  // materialized attention, per (head, 1024-row q block); S in wT8 slot
  for (int h = 0; h < 16; ++h) {
    const u16* qh = q_r + (size_t)h * 4096 * 128;
    const u16* kh = k_r + (size_t)h * 4096 * 128;
    const u16* vh = v_t + (size_t)h * 128 * 4096;
    for (int qb = 0; qb < 4; ++qb) {
      gemm_bt<<<dim3(32, 8), 256, 0, stream>>>(
          qh + (size_t)qb * 1024 * 128, kh, S, 1024, 4096, 128, 4096);
      row_softmax<<<dim3(256), 256, 0, stream>>>(S, qb * 1024);
      gemm_bt<<<dim3(1, 8), 256, 0, stream>>>(
          S, vh, attn + (size_t)qb * 1024 * 2048 + h * 128, 1024, 128, 4096,
          2048);
    }
  }

  // w_out^T (S slot dead now)
  transpose_in<<<tg, 256, 0, stream>>>(wo, wT8, flags, 2, 2048, 2048, 0LL);
  // out = attn @ w_out  -> fp32
  gemm_bt_f32<<<gg, 256, 0, stream>>>(attn, wT8, out, 4096, 2048, 2048, 2048);
}

// Round 7
// 801.163 us; speedup vs baseline: 9.3329x; 9.3329x over previous
//
#include <hip/hip_runtime.h>
#include <stdint.h>

typedef short bf16x8 __attribute__((ext_vector_type(8)));
typedef float f32x4 __attribute__((ext_vector_type(4)));
typedef unsigned short u16;

__device__ __forceinline__ float b2f(u16 u) {
  return __uint_as_float(((unsigned)u) << 16);
}
__device__ __forceinline__ u16 f2b(float f) {
  unsigned u = __float_as_uint(f);
  return (u16)((u + 0x7fffu + ((u >> 16) & 1u)) >> 16);  // RNE
}

#define NEGINF (-1.0e30f)

// ---------------------------------------------------------------- dtype sniff
// flags[i]=1 -> input i is fp32 (detected from raw u16 stream signatures).
__global__ void sniff5(const u16* x, const u16* wq, const u16* wo,
                       const u16* qg, const u16* kg, int* flags) {
  const u16* p;
  int S;
  switch (blockIdx.x) {
    case 0: p = x;  S = 2048; break;
    case 1: p = wq; S = 2048; break;
    case 2: p = wo; S = 2048; break;
    case 3: p = qg; S = 128;  break;
    default: p = kg; S = 128; break;
  }
  __shared__ int cbig, czero;
  if (threadIdx.x == 0) { cbig = 0; czero = 0; }
  __syncthreads();
  int cb = 0, cz = 0;
  for (int i = threadIdx.x; i < S; i += 256) {
    const u16 u = p[i];
    if (((u >> 7) & 0xFF) >= 0xC0) ++cb;
    if (!(i & 1) && u == 0) ++cz;
  }
  atomicAdd(&cbig, cb);
  atomicAdd(&czero, cz);
  __syncthreads();
  if (threadIdx.x == 0)
    flags[blockIdx.x] = (cbig > S / 32 || czero > 3 * S / 8) ? 1 : 0;
}

// ---------------------------------------------------------------- convert
__global__ __launch_bounds__(256) void conv_in(const void* __restrict__ src,
                                               u16* __restrict__ dst,
                                               const int* __restrict__ flags,
                                               int fidx, int n) {
  const int fp32 = flags[fidx];
  int i = blockIdx.x * 256 + threadIdx.x;
  const int stride = gridDim.x * 256;
  if (fp32) {
    const float* s = (const float*)src;
    for (; i < n; i += stride) dst[i] = f2b(s[i]);
  } else {
    const u16* s = (const u16*)src;
    for (; i < n; i += stride) dst[i] = s[i];
  }
}

// ---------------------------------------------------------------- transpose_in
// dst[c][r] = bf16(src[r*ss + c]); dual-dtype. 64x64 tiles.
__global__ __launch_bounds__(256) void transpose_in(
    const void* __restrict__ src, u16* __restrict__ dst,
    const int* __restrict__ flags, int fidx, int ss, int ds) {
  __shared__ u16 tile[64][65];
  const int fp32 = flags[fidx];
  const int rb = blockIdx.y * 64, cb = blockIdx.x * 64;
  const int cl = threadIdx.x & 63, r0 = threadIdx.x >> 6;
  if (fp32) {
    const float* s = (const float*)src;
#pragma unroll
    for (int i = 0; i < 16; ++i) {
      int r = r0 + i * 4;
      tile[r][cl] = f2b(s[(long long)(rb + r) * ss + cb + cl]);
    }
  } else {
    const u16* s = (const u16*)src;
#pragma unroll
    for (int i = 0; i < 16; ++i) {
      int r = r0 + i * 4;
      tile[r][cl] = s[(long long)(rb + r) * ss + cb + cl];
    }
  }
  __syncthreads();
#pragma unroll
  for (int i = 0; i < 16; ++i) {
    int r2 = r0 + i * 4;
    dst[(long long)(cb + r2) * ds + rb + cl] = tile[cl][r2];
  }
}

// ---------------------------------------------------------------- transpose
__global__ __launch_bounds__(256) void transpose_bf16(
    const u16* __restrict__ src, u16* __restrict__ dst, int ss, int ds,
    long long sz, long long dz) {
  __shared__ u16 tile[64][65];
  const u16* s = src + (long long)blockIdx.z * sz;
  u16* d = dst + (long long)blockIdx.z * dz;
  const int rb = blockIdx.y * 64, cb = blockIdx.x * 64;
  const int cl = threadIdx.x & 63, r0 = threadIdx.x >> 6;
#pragma unroll
  for (int i = 0; i < 16; ++i) {
    int r = r0 + i * 4;
    tile[r][cl] = s[(long long)(rb + r) * ss + cb + cl];
  }
  __syncthreads();
#pragma unroll
  for (int i = 0; i < 16; ++i) {
    int r2 = r0 + i * 4;
    d[(long long)(cb + r2) * ds + rb + cl] = tile[cl][r2];
  }
}

// ---------------------------------------------------------------- GEMM (bf16 out)
// C(MxN, stride ldc) = A(MxK) * Bt(NxK)^T, fp32 accum. 128x128 tile, BK=32.
__global__ __launch_bounds__(256) void gemm_bt(
    const u16* __restrict__ A, const u16* __restrict__ Bt, u16* __restrict__ C,
    int M, int N, int K, int ldc) {
  __shared__ __align__(16) u16 As[128 * 32];
  __shared__ __align__(16) u16 Bs[128 * 32];
  const int tid = threadIdx.x;
  const int w = tid >> 6, l = tid & 63;
  const int lane15 = l & 15, quad = l >> 4;
  const int m0 = blockIdx.y * 128, n0 = blockIdx.x * 128;
  const int wm = (w >> 1) * 64, wn = (w & 1) * 64;
  const int srow = w * 32 + (l >> 2);
  const int skoff = (l & 3) * 8;
  const u16* gA = A + (size_t)(m0 + srow) * K + skoff;
  const u16* gB = Bt + (size_t)(n0 + srow) * K + skoff;
  u16* lA = &As[w * 1024 + l * 8];
  u16* lB = &Bs[w * 1024 + l * 8];
  f32x4 acc[4][4] = {};
  const int nK = K >> 5;
  for (int kb = 0; kb < nK; ++kb) {
    bf16x8 a0 = *(const bf16x8*)gA;
    bf16x8 a1 = *(const bf16x8*)(gA + (size_t)16 * K);
    bf16x8 b0 = *(const bf16x8*)gB;
    bf16x8 b1 = *(const bf16x8*)(gB + (size_t)16 * K);
    __syncthreads();
    *(bf16x8*)lA = a0;
    *(bf16x8*)(lA + 16 * 32) = a1;
    *(bf16x8*)lB = b0;
    *(bf16x8*)(lB + 16 * 32) = b1;
    __syncthreads();
    bf16x8 af[4], bfr[4];
#pragma unroll
    for (int mi = 0; mi < 4; ++mi)
      af[mi] = *(const bf16x8*)&As[(wm + mi * 16 + lane15) * 32 + quad * 8];
#pragma unroll
    for (int ni = 0; ni < 4; ++ni)
      bfr[ni] = *(const bf16x8*)&Bs[(wn + ni * 16 + lane15) * 32 + quad * 8];
#pragma unroll
    for (int mi = 0; mi < 4; ++mi)
#pragma unroll
      for (int ni = 0; ni < 4; ++ni)
        acc[mi][ni] = __builtin_amdgcn_mfma_f32_16x16x32_bf16(
            af[mi], bfr[ni], acc[mi][ni], 0, 0, 0);
    gA += 32;
    gB += 32;
  }
#pragma unroll
  for (int mi = 0; mi < 4; ++mi)
#pragma unroll
    for (int ni = 0; ni < 4; ++ni)
#pragma unroll
      for (int r = 0; r < 4; ++r)
        C[(size_t)(m0 + wm + mi * 16 + quad * 4 + r) * ldc +
          (n0 + wn + ni * 16 + lane15)] = f2b(acc[mi][ni][r]);
}

// ---------------------------------------------------------------- GEMM (fp32 out)
__global__ __launch_bounds__(256) void gemm_bt_f32(
    const u16* __restrict__ A, const u16* __restrict__ Bt,
    float* __restrict__ C, int M, int N, int K, int ldc) {
  __shared__ __align__(16) u16 As[128 * 32];
  __shared__ __align__(16) u16 Bs[128 * 32];
  const int tid = threadIdx.x;
  const int w = tid >> 6, l = tid & 63;
  const int lane15 = l & 15, quad = l >> 4;
  const int m0 = blockIdx.y * 128, n0 = blockIdx.x * 128;
  const int wm = (w >> 1) * 64, wn = (w & 1) * 64;
  const int srow = w * 32 + (l >> 2);
  const int skoff = (l & 3) * 8;
  const u16* gA = A + (size_t)(m0 + srow) * K + skoff;
  const u16* gB = Bt + (size_t)(n0 + srow) * K + skoff;
  u16* lA = &As[w * 1024 + l * 8];
  u16* lB = &Bs[w * 1024 + l * 8];
  f32x4 acc[4][4] = {};
  const int nK = K >> 5;
  for (int kb = 0; kb < nK; ++kb) {
    bf16x8 a0 = *(const bf16x8*)gA;
    bf16x8 a1 = *(const bf16x8*)(gA + (size_t)16 * K);
    bf16x8 b0 = *(const bf16x8*)gB;
    bf16x8 b1 = *(const bf16x8*)(gB + (size_t)16 * K);
    __syncthreads();
    *(bf16x8*)lA = a0;
    *(bf16x8*)(lA + 16 * 32) = a1;
    *(bf16x8*)lB = b0;
    *(bf16x8*)(lB + 16 * 32) = b1;
    __syncthreads();
    bf16x8 af[4], bfr[4];
#pragma unroll
    for (int mi = 0; mi < 4; ++mi)
      af[mi] = *(const bf16x8*)&As[(wm + mi * 16 + lane15) * 32 + quad * 8];
#pragma unroll
    for (int ni = 0; ni < 4; ++ni)
      bfr[ni] = *(const bf16x8*)&Bs[(wn + ni * 16 + lane15) * 32 + quad * 8];
#pragma unroll
    for (int mi = 0; mi < 4; ++mi)
#pragma unroll
      for (int ni = 0; ni < 4; ++ni)
        acc[mi][ni] = __builtin_amdgcn_mfma_f32_16x16x32_bf16(
            af[mi], bfr[ni], acc[mi][ni], 0, 0, 0);
    gA += 32;
    gB += 32;
  }
#pragma unroll
  for (int mi = 0; mi < 4; ++mi)
#pragma unroll
    for (int ni = 0; ni < 4; ++ni)
#pragma unroll
      for (int r = 0; r < 4; ++r)
        C[(size_t)(m0 + wm + mi * 16 + quad * 4 + r) * ldc +
          (n0 + wn + ni * 16 + lane15)] = acc[mi][ni][r];
}

// ---------------------------------------------------------------- RMSNorm+RoPE
__global__ __launch_bounds__(256) void rms_rope(
    const u16* __restrict__ in, const u16* __restrict__ gamma,
    u16* __restrict__ outr) {
  const int wid = blockIdx.x * 4 + (threadIdx.x >> 6);
  const int l = threadIdx.x & 63;
  const int n = wid >> 4;
  const int h = wid & 15;
  const u16* base = in + (size_t)n * 2048 + h * 128;
  float a = b2f(base[l]), b = b2f(base[l + 64]);
  float ssum = a * a + b * b;
#pragma unroll
  for (int m = 1; m < 64; m <<= 1) ssum += __shfl_xor(ssum, m);
  const float r = rsqrtf(ssum * (1.0f / 128.0f) + 1e-6f);
  a *= r * b2f(gamma[l]);
  b *= r * b2f(gamma[l + 64]);
  const float inv = __expf(-(float)l * 0.14391156831212787f);  // 10000^(-l/64)
  float s, c;
  sincosf((float)n * inv, &s, &c);
  const size_t o = ((size_t)h * 4096 + n) * 128 + l;
  outr[o] = f2b(a * c - b * s);
  outr[o + 64] = f2b(b * c + a * s);
}

// ---------------------------------------------------------------- flash attn
// causal, BM=128 q/block, BN=64 k/iter, 4 waves (32 rows each).
// q_r,k_r: (h, n, d); v_t: (h, d, n); attn: (n, h*128+d) bf16.
__global__ __launch_bounds__(256, 2) void flash_attn(
    const u16* __restrict__ q_r, const u16* __restrict__ k_r,
    const u16* __restrict__ v_t, u16* __restrict__ attn) {
  __shared__ __align__(16) u16 Kt[64 * 128];  // [key][hd]
  __shared__ __align__(16) u16 Vt[128 * 64];  // [hd][key]
  __shared__ __align__(16) u16 Pt[128 * 64];  // [q][key]
  const int h = blockIdx.y;
  const int qt = 31 - (int)blockIdx.x;  // big tiles first
  const int m0 = qt * 128;
  const int tid = threadIdx.x, w = tid >> 6, l = tid & 63;
  const int lane15 = l & 15, quad = l >> 4;

  bf16x8 aq[2][4];
#pragma unroll
  for (int mi = 0; mi < 2; ++mi)
#pragma unroll
    for (int ks = 0; ks < 4; ++ks)
      aq[mi][ks] = *(const bf16x8*)&q_r[((size_t)h * 4096 + m0 + w * 32 +
                                         mi * 16 + lane15) * 128 +
                                        ks * 32 + quad * 8];

  f32x4 acc_o[2][8] = {};
  float m_i[2][4], l_i[2][4];
#pragma unroll
  for (int mi = 0; mi < 2; ++mi)
#pragma unroll
    for (int r = 0; r < 4; ++r) {
      m_i[mi][r] = NEGINF;
      l_i[mi][r] = 0.f;
    }

  for (int j0 = 0; j0 <= m0 + 64; j0 += 64) {
    // stage K,V: global->reg (pre-barrier), reg->LDS
    bf16x8 kv[4], vv[4];
#pragma unroll
    for (int i = 0; i < 4; ++i) {
      const int c = (i * 4 + w) * 64 + l;
      kv[i] = *(const bf16x8*)&k_r[((size_t)h * 4096 + j0 + (c >> 4)) * 128 +
                                   (c & 15) * 8];
      vv[i] = *(const bf16x8*)&v_t[((size_t)h * 128 + (c >> 3)) * 4096 + j0 +
                                   (c & 7) * 8];
    }
    __syncthreads();
#pragma unroll
    for (int i = 0; i < 4; ++i) {
      *(bf16x8*)&Kt[(i * 4 + w) * 512 + l * 8] = kv[i];
      *(bf16x8*)&Vt[(i * 4 + w) * 512 + l * 8] = vv[i];
    }
    __syncthreads();

    // S = Q K^T
    f32x4 s2[2][4] = {};
#pragma unroll
    for (int ni = 0; ni < 4; ++ni) {
#pragma unroll
      for (int ks = 0; ks < 4; ++ks) {
        bf16x8 bk =
            *(const bf16x8*)&Kt[(ni * 16 + lane15) * 128 + ks * 32 + quad * 8];
        s2[0][ni] = __builtin_amdgcn_mfma_f32_16x16x32_bf16(aq[0][ks], bk,
                                                            s2[0][ni], 0, 0, 0);
        s2[1][ni] = __builtin_amdgcn_mfma_f32_16x16x32_bf16(aq[1][ks], bk,
                                                            s2[1][ni], 0, 0, 0);
      }
    }

    const float sc = 0.08838834764831845f;  // 1/sqrt(128)
    const bool mt = (j0 >= m0);
#pragma unroll
    for (int mi = 0; mi < 2; ++mi) {
#pragma unroll
      for (int r = 0; r < 4; ++r) {
        const int lrow = w * 32 + mi * 16 + quad * 4 + r;
        float xv[4], mx = NEGINF;
#pragma unroll
        for (int ni = 0; ni < 4; ++ni) {
          float xx = s2[mi][ni][r] * sc;
          if (mt && (j0 + ni * 16 + lane15 > m0 + lrow)) xx = NEGINF;
          xv[ni] = xx;
          mx = fmaxf(mx, xx);
        }
#pragma unroll
        for (int mk = 1; mk < 16; mk <<= 1) mx = fmaxf(mx, __shfl_xor(mx, mk));
        const float mold = m_i[mi][r];
        const float mnew = fmaxf(mold, mx);
        const float alpha = __expf(mold - mnew);
        float rs = 0.f;
#pragma unroll
        for (int ni = 0; ni < 4; ++ni) {
          const float p = __expf(xv[ni] - mnew);
          Pt[(size_t)lrow * 64 + ni * 16 + lane15] = f2b(p);
          rs += p;
        }
#pragma unroll
        for (int mk = 1; mk < 16; mk <<= 1) rs += __shfl_xor(rs, mk);
        l_i[mi][r] = l_i[mi][r] * alpha + rs;
        m_i[mi][r] = mnew;
#pragma unroll
        for (int ni = 0; ni < 8; ++ni) acc_o[mi][ni][r] *= alpha;
      }
    }
    __syncthreads();

    // O += P V
#pragma unroll
    for (int ks = 0; ks < 2; ++ks) {
      bf16x8 ap0 = *(const bf16x8*)&Pt[(size_t)(w * 32 + lane15) * 64 +
                                       ks * 32 + quad * 8];
      bf16x8 ap1 = *(const bf16x8*)&Pt[(size_t)(w * 32 + 16 + lane15) * 64 +
                                       ks * 32 + quad * 8];
#pragma unroll
      for (int ni = 0; ni < 8; ++ni) {
        bf16x8 bv =
            *(const bf16x8*)&Vt[(ni * 16 + lane15) * 64 + ks * 32 + quad * 8];
        acc_o[0][ni] = __builtin_amdgcn_mfma_f32_16x16x32_bf16(
            ap0, bv, acc_o[0][ni], 0, 0, 0);
        acc_o[1][ni] = __builtin_amdgcn_mfma_f32_16x16x32_bf16(
            ap1, bv, acc_o[1][ni], 0, 0, 0);
      }
    }
  }

#pragma unroll
  for (int mi = 0; mi < 2; ++mi)
#pragma unroll
    for (int ni = 0; ni < 8; ++ni)
#pragma unroll
      for (int r = 0; r < 4; ++r)
        attn[(size_t)(m0 + w * 32 + mi * 16 + quad * 4 + r) * 2048 + h * 128 +
             ni * 16 + lane15] = f2b(acc_o[mi][ni][r] / l_i[mi][r]);
}

// ---------------------------------------------------------------- launch
// ws (58.72 MB, proven safe in r6):
//   A0 [0,16.8M):    xb      -> q_r
//   A1 [16.8,33.6M): k_buf   -> attn
//   A2 [33.6,58.72M): wT (6144x2048, 25.2M) -> v_t [33.6,50.3) + woT [50.3,58.72)
//   flags/gammas at 58.72M
// d_out (fp32, 33.5 MB):
//   D0 [0,16.8M):    q_buf   -> k_r      (dead before final gemm writes)
//   D1 [16.8,33.5M): v_buf               (dead before final gemm writes)
// Final gemm reads only ws -> no read/write race on d_out.
extern "C" void kernel_launch(void* const* d_in, const int* in_sizes, int n_in,
                              void* d_out, int out_size, void* d_ws,
                              size_t ws_size, hipStream_t stream) {
  (void)out_size; (void)ws_size;
  int ix = 0, iwq = 1, iwo = 2, ig1 = 3, ig2 = 4;
  {
    int g1 = -1, g2 = -1, xx = -1, wqq = -1, woo = -1;
    for (int i = 0; i < n_in; ++i) {
      const int s = in_sizes[i];
      if (s == 8388608) xx = i;
      else if (s == 12582912) wqq = i;
      else if (s == 4194304) woo = i;
      else if (s == 128) { if (g1 < 0) g1 = i; else g2 = i; }
    }
    if (xx >= 0 && wqq >= 0 && woo >= 0 && g1 >= 0 && g2 >= 0) {
      ix = xx; iwq = wqq; iwo = woo; ig1 = g1; ig2 = g2;
    }
  }
  const void* x = d_in[ix];
  const void* wq = d_in[iwq];
  const void* wo = d_in[iwo];
  const void* qg = d_in[ig1];
  const void* kg = d_in[ig2];
  float* out = (float*)d_out;
  char* ws = (char*)d_ws;
  u16* xb = (u16*)(ws);
  u16* k_buf = (u16*)(ws + 16777216LL);
  u16* wT = (u16*)(ws + 33554432LL);    // 6144x2048
  int* flags = (int*)(ws + 58720256LL);
  u16* gq_b = (u16*)(ws + 58720512LL);
  u16* gk_b = (u16*)(ws + 58721024LL);
  u16* q_r = (u16*)(ws);                // over dead xb
  u16* attn = (u16*)(ws + 16777216LL);  // over dead k_buf
  u16* v_t = (u16*)(ws + 33554432LL);   // over dead wT (first 16.8M)
  u16* woT = (u16*)(ws + 50331648LL);   // over dead wT (last 8.4M)
  u16* q_buf = (u16*)d_out;             // D0
  u16* k_r = (u16*)d_out;               // D0 (after q_buf dead)
  u16* v_buf = (u16*)d_out + 8388608;   // D1

  const dim3 gg(16, 32);
  sniff5<<<5, 256, 0, stream>>>((const u16*)x, (const u16*)wq, (const u16*)wo,
                                (const u16*)qg, (const u16*)kg, flags);
  conv_in<<<8192, 256, 0, stream>>>(x, xb, flags, 0, 4096 * 2048);
  conv_in<<<1, 256, 0, stream>>>(qg, gq_b, flags, 3, 128);
  conv_in<<<1, 256, 0, stream>>>(kg, gk_b, flags, 4, 128);
  // wq^T: (2048x6144) -> wT (6144x2048)
  transpose_in<<<dim3(96, 32), 256, 0, stream>>>(wq, wT, flags, 1, 6144, 2048);
  // q/k/v projections (Bt = wT row-slices)
  gemm_bt<<<gg, 256, 0, stream>>>(xb, wT, q_buf, 4096, 2048, 2048, 2048);
  gemm_bt<<<gg, 256, 0, stream>>>(xb, wT + 4194304LL, k_buf, 4096, 2048, 2048,
                                  2048);
  gemm_bt<<<gg, 256, 0, stream>>>(xb, wT + 8388608LL, v_buf, 4096, 2048, 2048,
                                  2048);
  // rmsnorm + rope + repack to (h,n,d); q_r over dead xb, k_r over dead q_buf
  rms_rope<<<dim3(16384), 256, 0, stream>>>(q_buf, gq_b, q_r);
  rms_rope<<<dim3(16384), 256, 0, stream>>>(k_buf, gk_b, k_r);
  // v -> v_t (h, d, n), over dead wT
  transpose_bf16<<<dim3(2, 64, 16), 256, 0, stream>>>(v_buf, v_t, 2048, 4096,
                                                      128LL, 524288LL);
  // w_out^T
  transpose_in<<<dim3(32, 32), 256, 0, stream>>>(wo, woT, flags, 2, 2048, 2048);
  // causal flash attention -> attn (n, 2048), over dead k_buf
  flash_attn<<<dim3(32, 16), 256, 0, stream>>>(q_r, k_r, v_t, attn);
  // out = attn @ w_out -> fp32 d_out (reads only ws)
  gemm_bt_f32<<<gg, 256, 0, stream>>>(attn, woT, out, 4096, 2048, 2048, 2048);
}